// Round 1
// baseline (2425.780 us; speedup 1.0000x reference)
//
#include <hip/hip_runtime.h>

// Game-of-Life CNN: 21 layers of [iterated-pad-31 + conv k=32 s=2] + 1x1 out conv.
// Each layer == GEMM M=32(co) x N=16384(b,oy,ox) x K=32768(c,ky,kx) with B
// gathered via the pad index map m(). f16 MFMA 16x16x32, fp32 accumulate.

typedef _Float16 f16;
typedef _Float16 f16x8 __attribute__((ext_vector_type(8)));
typedef _Float16 f16x4 __attribute__((ext_vector_type(4)));
typedef float f32x4 __attribute__((ext_vector_type(4)));

// iterated wrap-pad index map, j in [0,94): middle j-31; borders alternate 31/0.
__device__ __forceinline__ int mwrap(int j) {
  int t = j - 31;
  if ((unsigned)t <= 31u) return t;          // j in [31,62]
  if (t < 0) return ((31 - j) & 1) ? 31 : 0; // left border
  return ((j - 62) & 1) ? 0 : 31;            // right border
}

// A-chunk LDS row stride: 40 f16 (80B) to break 64B power-of-2 bank stride.
#define AST 40

template <int CIN, bool RELU, bool AF16>
__global__ __launch_bounds__(512, 2) void gemm_layer(
    const void* __restrict__ AwV,      // weights [32][CIN*1024], f16 or fp32
    const f16* __restrict__ hin,       // [16][CIN][32][32]
    const float* __restrict__ bias,    // [32]
    f16* __restrict__ hout) {          // [16][32][32][32]
  constexpr int K = CIN * 1024;
  constexpr int ITERS = CIN * 8;       // K-chunks (32 wide) per quarter

  __shared__ __align__(16) f16 Abuf[2][4][32 * AST]; // [dbuf][kq][row*AST+k]
  __shared__ __align__(16) f16 Rbuf[2][8][96];       // [dbuf][kq*2+p][x]
  __shared__ float Red[6144];                        // 2p x 3kq x 4tiles x 256

  const int tid = threadIdx.x;
  const int lane = tid & 63;
  const int w = tid >> 6;
  const int kq = w >> 1;   // K-quarter 0..3
  const int p = w & 1;     // which (b,oy) pair
  const int t16 = lane & 15;
  const int q = lane >> 4; // quad 0..3

  const int pair0 = blockIdx.x * 2;
  const int pairw = pair0 + p;
  const int bw = pairw >> 5, oyw = pairw & 31;

  // --- A staging decode: 512 threads x 8 f16 (one 16B unit each) ---
  const int kqA = tid >> 7;
  const int rowA = (tid >> 2) & 31;
  const int segA = tid & 3;

  // --- Row staging decode: 8 rows x 96 = 768 f16 units ---
  const int rR0 = tid / 96, xR0 = tid - rR0 * 96;
  const int mx0 = (xR0 < 94) ? mwrap(xR0) : 0;
  const int kqR0 = rR0 >> 1, pR0 = rR0 & 1;
  const int pr0 = pair0 + pR0, bb0 = pr0 >> 5, oy0 = pr0 & 31;
  const int u1 = 512 + tid;
  const int rR1 = u1 / 96, xR1 = u1 - rR1 * 96;
  const int mx1 = (xR1 < 94) ? mwrap(xR1) : 0;
  const int kqR1 = rR1 >> 1, pR1 = rR1 & 1;
  const int pr1 = pair0 + pR1, bb1 = pr1 >> 5, oy1 = pr1 & 31;

  f32x4 acc[2][2] = {}; // [mi][hx]

  // staged registers
  f32x4 af0 = {}, af1 = {};
  f16x8 a16 = {};
  f16 rv0 = (f16)0.f, rv1 = (f16)0.f;

  auto stage_load = [&](int inx) {
    const int cky = kqA * ITERS + inx;
    if constexpr (AF16) {
      const f16* Aw = (const f16*)AwV;
      a16 = *(const f16x8*)(Aw + (size_t)rowA * K + cky * 32 + segA * 8);
    } else {
      const float* Aw = (const float*)AwV;
      const float* s = Aw + (size_t)rowA * K + cky * 32 + segA * 8;
      af0 = *(const f32x4*)(s);
      af1 = *(const f32x4*)(s + 4);
    }
    {
      const int ck = kqR0 * ITERS + inx;
      const int c = ck >> 5, ky = ck & 31;
      const int ry = mwrap(2 * oy0 + ky);
      rv0 = (xR0 < 94) ? hin[(bb0 * CIN + c) * 1024 + ry * 32 + mx0] : (f16)0.f;
    }
    if (tid < 256) {
      const int ck = kqR1 * ITERS + inx;
      const int c = ck >> 5, ky = ck & 31;
      const int ry = mwrap(2 * oy1 + ky);
      rv1 = (xR1 < 94) ? hin[(bb1 * CIN + c) * 1024 + ry * 32 + mx1] : (f16)0.f;
    }
  };

  auto stage_write = [&](int nb) {
    if constexpr (AF16) {
      *(f16x8*)&Abuf[nb][kqA][rowA * AST + segA * 8] = a16;
    } else {
      f16x8 v;
      v[0] = (f16)af0[0]; v[1] = (f16)af0[1]; v[2] = (f16)af0[2]; v[3] = (f16)af0[3];
      v[4] = (f16)af1[0]; v[5] = (f16)af1[1]; v[6] = (f16)af1[2]; v[7] = (f16)af1[3];
      *(f16x8*)&Abuf[nb][kqA][rowA * AST + segA * 8] = v;
    }
    Rbuf[nb][rR0][xR0] = rv0;
    if (tid < 256) Rbuf[nb][rR1][xR1] = rv1;
  };

  stage_load(0);
  stage_write(0);
  __syncthreads();

#pragma unroll 2
  for (int i = 0; i < ITERS; ++i) {
    const int buf = i & 1;
    if (i + 1 < ITERS) stage_load(i + 1);
    {
      const f16* Ab = Abuf[buf][kq];
      // A-frag: A[m = lane&15][k = q*8+j]
      f16x8 a0 = *(const f16x8*)(Ab + t16 * AST + q * 8);
      f16x8 a1 = *(const f16x8*)(Ab + (16 + t16) * AST + q * 8);
      // B-frag: B[k = kx][n = ox] = row[2*ox + kx] -> dwords at ox + 4q + d
      const int* Rw = (const int*)&Rbuf[buf][kq * 2 + p][0];
      const int bi = t16 + 4 * q;
      int4 w0 = {Rw[bi], Rw[bi + 1], Rw[bi + 2], Rw[bi + 3]};
      int4 w1 = {Rw[bi + 16], Rw[bi + 17], Rw[bi + 18], Rw[bi + 19]};
      f16x8 b0 = __builtin_bit_cast(f16x8, w0);
      f16x8 b1 = __builtin_bit_cast(f16x8, w1);
      acc[0][0] = __builtin_amdgcn_mfma_f32_16x16x32_f16(a0, b0, acc[0][0], 0, 0, 0);
      acc[1][0] = __builtin_amdgcn_mfma_f32_16x16x32_f16(a1, b0, acc[1][0], 0, 0, 0);
      acc[0][1] = __builtin_amdgcn_mfma_f32_16x16x32_f16(a0, b1, acc[0][1], 0, 0, 0);
      acc[1][1] = __builtin_amdgcn_mfma_f32_16x16x32_f16(a1, b1, acc[1][1], 0, 0, 0);
    }
    if (i + 1 < ITERS) stage_write(buf ^ 1);
    __syncthreads();
  }

  // 4-way K-quarter reduction through LDS
  if (kq != 0) {
#pragma unroll
    for (int mi = 0; mi < 2; ++mi)
#pragma unroll
      for (int hx = 0; hx < 2; ++hx) {
        float* dst = &Red[(((p * 3 + (kq - 1)) * 4) + mi * 2 + hx) * 256];
#pragma unroll
        for (int r = 0; r < 4; ++r) dst[(q * 4 + r) * 16 + t16] = acc[mi][hx][r];
      }
  }
  __syncthreads();
  if (kq == 0) {
#pragma unroll
    for (int mi = 0; mi < 2; ++mi)
#pragma unroll
      for (int hx = 0; hx < 2; ++hx) {
#pragma unroll
        for (int kk = 0; kk < 3; ++kk) {
          const float* src = &Red[(((p * 3 + kk) * 4) + mi * 2 + hx) * 256];
#pragma unroll
          for (int r = 0; r < 4; ++r) acc[mi][hx][r] += src[(q * 4 + r) * 16 + t16];
        }
#pragma unroll
        for (int r = 0; r < 4; ++r) {
          const int co = mi * 16 + q * 4 + r; // C/D: row = q*4+r, col = t16
          float v = acc[mi][hx][r] + bias[co];
          if (RELU) v = fmaxf(v, 0.f);
          const int ox = hx * 16 + t16;
          hout[((bw * 32 + co) * 32 + oyw) * 32 + ox] = (f16)v;
        }
      }
  }
}

__global__ void convert_x_kernel(const float* __restrict__ x, f16* __restrict__ xh) {
  int i = blockIdx.x * 256 + threadIdx.x; // 16384 total
  xh[i] = (f16)x[i];
}

__global__ void convert_w_kernel(const float* __restrict__ in_w,
                                 const float* __restrict__ convs_w,
                                 f16* __restrict__ AwIn, f16* __restrict__ AwH) {
  const int total4 = (32768 + 20971520) / 4;
  for (int j = blockIdx.x * blockDim.x + threadIdx.x; j < total4;
       j += gridDim.x * blockDim.x) {
    int e = j * 4;
    const float* src;
    f16* dst;
    int off;
    if (e < 32768) { src = in_w; dst = AwIn; off = e; }
    else { src = convs_w; dst = AwH; off = e - 32768; }
    f32x4 v = *(const f32x4*)(src + off);
    f16x4 o;
    o[0] = (f16)v[0]; o[1] = (f16)v[1]; o[2] = (f16)v[2]; o[3] = (f16)v[3];
    *(f16x4*)(dst + off) = o;
  }
}

__global__ void out_conv_kernel(const f16* __restrict__ h,
                                const float* __restrict__ ow,
                                const float* __restrict__ ob,
                                float* __restrict__ out) {
  int o = blockIdx.x * 256 + threadIdx.x; // 16384
  int b = o >> 10, rem = o & 1023;
  const f16* hb = h + b * 32768 + rem;
  float s = ob[0];
#pragma unroll
  for (int c = 0; c < 32; ++c) s += ow[c] * (float)hb[c * 1024];
  out[o] = s;
}

extern "C" void kernel_launch(void* const* d_in, const int* in_sizes, int n_in,
                              void* d_out, int out_size, void* d_ws,
                              size_t ws_size, hipStream_t stream) {
  const float* x = (const float*)d_in[0];
  const float* in_w = (const float*)d_in[1];
  const float* in_b = (const float*)d_in[2];
  const float* convs_w = (const float*)d_in[3];
  const float* convs_b = (const float*)d_in[4];
  const float* out_w = (const float*)d_in[5];
  const float* out_b = (const float*)d_in[6];
  float* out = (float*)d_out;

  char* ws = (char*)d_ws;
  f16* xh = (f16*)ws;                       // 32 KB
  f16* hA = (f16*)(ws + 32768);             // 1 MB
  f16* hB = (f16*)(ws + 32768 + 1048576);   // 1 MB
  const size_t small_need = 32768 + 2 * 1048576ull;
  f16* AwIn = (f16*)(ws + small_need);              // 64 KB
  f16* AwH = (f16*)(ws + small_need + 65536);       // 40 MB
  const size_t big_need = small_need + 65536 + 41943040ull;
  const bool pre = (ws_size >= big_need);

  convert_x_kernel<<<64, 256, 0, stream>>>(x, xh);
  if (pre) convert_w_kernel<<<2048, 256, 0, stream>>>(in_w, convs_w, AwIn, AwH);

  // in-conv: CIN=1, no ReLU
  if (pre)
    gemm_layer<1, false, true><<<256, 512, 0, stream>>>(AwIn, xh, in_b, hA);
  else
    gemm_layer<1, false, false><<<256, 512, 0, stream>>>(in_w, xh, in_b, hA);

  f16* cur = hA;
  f16* nxt = hB;
  for (int l = 0; l < 20; ++l) {
    const void* Aw = pre ? (const void*)(AwH + (size_t)l * 1048576)
                         : (const void*)(convs_w + (size_t)l * 1048576);
    if (pre)
      gemm_layer<32, true, true><<<256, 512, 0, stream>>>(Aw, cur, convs_b + l * 32, nxt);
    else
      gemm_layer<32, true, false><<<256, 512, 0, stream>>>(Aw, cur, convs_b + l * 32, nxt);
    f16* t = cur; cur = nxt; nxt = t;
  }

  out_conv_kernel<<<64, 256, 0, stream>>>(cur, out_w, out_b, out);
}

// Round 2
// 1021.602 us; speedup vs baseline: 2.3745x; 2.3745x over previous
//
#include <hip/hip_runtime.h>

// GoL CNN v3: per layer GEMM M=32(co) x N=16384(b,oy,ox) x K=CIN*1024 via
// mfma_f32_32x32x16_f16. A (weights) frag-major in ws, loaded per-wave from
// L2 (no LDS). B (activations) from x-padded global hpad -> small LDS rowbuf.
// 8-way K-split across waves, one-shot LDS reduce, fused epilogue writes hpad.

typedef _Float16 f16;
typedef _Float16 f16x8 __attribute__((ext_vector_type(8)));
typedef float f32x4 __attribute__((ext_vector_type(4)));
typedef float f32x16 __attribute__((ext_vector_type(16)));

// iterated wrap-pad index map, j in [0,94): middle j-31; borders alternate.
__device__ __forceinline__ int mwrap(int j) {
  int t = j - 31;
  if ((unsigned)t <= 31u) return t;          // middle
  if (t < 0) return (j & 1) ? 0 : 31;        // left border: even j->31, odd->0
  return (j & 1) ? 0 : 31;                   // right border: odd j->0, even->31
}

// hpad layout: [16b][32ch][32y][96x] f16 (x' in [0,94) valid)
// Wf frag-major: per layer, chunk=(c*32+ky)*2+kxh, then [lane(64)][8 f16]
//   lane: co=lane&31, s=lane>>5; elements w[co][c][ky][kxh*16+s*8+j]

template <int CIN, bool RELU, bool PRE>
__global__ __launch_bounds__(512, 2) void gemm3(
    const void* __restrict__ Wv,       // PRE: f16 frag-major; else fp32 raw
    const f16* __restrict__ hp_in,     // [16][CIN][32][96]
    const float* __restrict__ bias,    // [32]
    f16* __restrict__ hp_out) {        // [16][32][32][96]
  __shared__ __align__(16) f16 rowbuf[2][32][96];  // 12 KB
  __shared__ float Red[8][2][1024];                // 64 KB

  const int tid = threadIdx.x;
  const int lane = tid & 63;
  const int w = tid >> 6;        // wave 0..7: owns ky in {w, w+8, w+16, w+24}
  const int ox = lane & 31;      // B n-index / A m-index (co)
  const int s = lane >> 5;       // k-half within mfma

  const int pair0 = blockIdx.x * 2;
  const int b = pair0 >> 5;
  const int oy0 = pair0 & 31;    // pair0 even -> oy0, oy0+1 same batch

  // row staging decode: 384 units of f16x8 cover 32 rows x 96
  const int rrow = tid / 12, rseg = tid - rrow * 12;  // valid if tid<384

  f32x16 acc0 = {}, acc1 = {};   // per pair
  f16x8 Acur[8], Anxt[8];
  f16x8 stg = {};

  auto loadA = [&](int c, f16x8* dst) {
#pragma unroll
    for (int kyi = 0; kyi < 4; ++kyi) {
#pragma unroll
      for (int kxh = 0; kxh < 2; ++kxh) {
        const int ky = w + 8 * kyi;
        const int chunk = (c * 32 + ky) * 2 + kxh;
        if constexpr (PRE) {
          const f16* Wl = (const f16*)Wv;
          dst[kyi * 2 + kxh] = *(const f16x8*)(Wl + (size_t)chunk * 512 + lane * 8);
        } else {
          const float* Wl = (const float*)Wv;
          const float* sp = Wl + (((size_t)(ox * CIN + c) * 32 + ky) * 32 + kxh * 16 + s * 8);
          f32x4 u0 = *(const f32x4*)sp;
          f32x4 u1 = *(const f32x4*)(sp + 4);
          f16x8 v;
          v[0] = (f16)u0[0]; v[1] = (f16)u0[1]; v[2] = (f16)u0[2]; v[3] = (f16)u0[3];
          v[4] = (f16)u1[0]; v[5] = (f16)u1[1]; v[6] = (f16)u1[2]; v[7] = (f16)u1[3];
          dst[kyi * 2 + kxh] = v;
        }
      }
    }
  };
  auto loadRow = [&](int c) {
    if (tid < 384)
      stg = *(const f16x8*)(hp_in + ((size_t)(b * CIN + c) * 32 + rrow) * 96 + rseg * 8);
  };
  auto writeRow = [&](int nb) {
    if (tid < 384) *(f16x8*)(&rowbuf[nb][rrow][rseg * 8]) = stg;
  };

  loadA(0, Acur);
  loadRow(0);
  writeRow(0);
  __syncthreads();

  for (int c = 0; c < CIN; ++c) {
    const int buf = c & 1;
    if (c + 1 < CIN) {
      loadA(c + 1, Anxt);
      loadRow(c + 1);
    }
#pragma unroll
    for (int kyi = 0; kyi < 4; ++kyi) {
      const int ky = w + 8 * kyi;
      const int y0 = mwrap(2 * oy0 + ky);
      const int y1 = mwrap(2 * (oy0 + 1) + ky);
      const int* R0 = (const int*)(&rowbuf[buf][y0][0]);
      const int* R1 = (const int*)(&rowbuf[buf][y1][0]);
#pragma unroll
      for (int kxh = 0; kxh < 2; ++kxh) {
        const int bi = ox + 4 * s + 8 * kxh;
        int4 b0w, b1w;
        b0w.x = R0[bi]; b0w.y = R0[bi + 1]; b0w.z = R0[bi + 2]; b0w.w = R0[bi + 3];
        b1w.x = R1[bi]; b1w.y = R1[bi + 1]; b1w.z = R1[bi + 2]; b1w.w = R1[bi + 3];
        f16x8 bf0 = __builtin_bit_cast(f16x8, b0w);
        f16x8 bf1 = __builtin_bit_cast(f16x8, b1w);
        const f16x8 a = Acur[kyi * 2 + kxh];
        acc0 = __builtin_amdgcn_mfma_f32_32x32x16_f16(a, bf0, acc0, 0, 0, 0);
        acc1 = __builtin_amdgcn_mfma_f32_32x32x16_f16(a, bf1, acc1, 0, 0, 0);
      }
    }
    if (c + 1 < CIN) {
      writeRow(buf ^ 1);
#pragma unroll
      for (int u = 0; u < 8; ++u) Acur[u] = Anxt[u];
    }
    __syncthreads();
  }

  // one-shot 8-way K reduction: every wave dumps, all 512 threads re-reduce
#pragma unroll
  for (int r = 0; r < 16; ++r) {
    Red[w][0][r * 64 + lane] = acc0[r];
    Red[w][1][r * 64 + lane] = acc1[r];
  }
  __syncthreads();

#pragma unroll
  for (int k4 = 0; k4 < 4; ++k4) {
    const int o = tid + 512 * k4;          // 2048 outputs: [p][co][ox]
    const int p = o >> 10, co = (o >> 5) & 31, oxx = o & 31;
    const int idx = ((co & 3) + 4 * (co >> 3)) * 64 + ((co >> 2) & 1) * 32 + oxx;
    float v = bias[co];
#pragma unroll
    for (int w8 = 0; w8 < 8; ++w8) v += Red[w8][p][idx];
    if (RELU) v = fmaxf(v, 0.f);
    const f16 hv = (f16)v;
    f16* base = hp_out + ((size_t)(b * 32 + co) * 32 + (oy0 + p)) * 96;
    base[oxx + 31] = hv;
    if (oxx == 0) {
#pragma unroll
      for (int j = 1; j <= 29; j += 2) base[j] = hv;
#pragma unroll
      for (int j = 63; j <= 93; j += 2) base[j] = hv;
    }
    if (oxx == 31) {
#pragma unroll
      for (int j = 0; j <= 30; j += 2) base[j] = hv;
#pragma unroll
      for (int j = 64; j <= 92; j += 2) base[j] = hv;
    }
  }
}

// x (fp32 [16][1][32][32]) -> xpad f16 [16][1][32][96]
__global__ void pad_x_kernel(const float* __restrict__ x, f16* __restrict__ xp) {
  const int i = blockIdx.x * 256 + threadIdx.x;  // 16*32*94 = 48128
  if (i >= 48128) return;
  const int bq = i / 3008, r = i - bq * 3008;
  const int y = r / 94, j = r - y * 94;
  xp[bq * 3072 + y * 96 + j] = (f16)x[(bq * 32 + y) * 32 + mwrap(j)];
}

// build frag-major f16 weights: in_w (64 chunks) + 20 hidden layers (2048 each)
__global__ void convert_w3(const float* __restrict__ in_w,
                           const float* __restrict__ convs_w,
                           f16* __restrict__ WfIn, f16* __restrict__ WfH) {
  const int total = 4096 + 20 * 131072;  // units of (chunk,lane)
  for (int g = blockIdx.x * blockDim.x + threadIdx.x; g < total;
       g += gridDim.x * blockDim.x) {
    const float* src;
    f16* dst;
    int chunk, lanE, c, ky, kxh;
    if (g < 4096) {
      chunk = g >> 6; lanE = g & 63;
      kxh = chunk & 1; ky = chunk >> 1; c = 0;
      const int co = lanE & 31, ss = lanE >> 5;
      src = in_w + ((size_t)(co * 1 + 0) * 32 + ky) * 32 + kxh * 16 + ss * 8;
      dst = WfIn + (size_t)chunk * 512 + lanE * 8;
    } else {
      const int h = g - 4096;
      const int layer = h >> 17, r = h & 131071;
      chunk = r >> 6; lanE = r & 63;
      kxh = chunk & 1;
      const int t = chunk >> 1;
      ky = t & 31; c = t >> 5;
      const int co = lanE & 31, ss = lanE >> 5;
      src = convs_w + (size_t)layer * 1048576 +
            ((size_t)(co * 32 + c) * 32 + ky) * 32 + kxh * 16 + ss * 8;
      dst = WfH + (size_t)layer * 1048576 + (size_t)chunk * 512 + lanE * 8;
    }
    f32x4 u0 = *(const f32x4*)src;
    f32x4 u1 = *(const f32x4*)(src + 4);
    f16x8 v;
    v[0] = (f16)u0[0]; v[1] = (f16)u0[1]; v[2] = (f16)u0[2]; v[3] = (f16)u0[3];
    v[4] = (f16)u1[0]; v[5] = (f16)u1[1]; v[6] = (f16)u1[2]; v[7] = (f16)u1[3];
    *(f16x8*)dst = v;
  }
}

// 1x1 out conv from hpad final: out[b][0][oy][ox] fp32
__global__ void out_conv3(const f16* __restrict__ hp,
                          const float* __restrict__ ow,
                          const float* __restrict__ ob,
                          float* __restrict__ out) {
  const int o = blockIdx.x * 256 + threadIdx.x;  // 16384
  const int b = o >> 10, oy = (o >> 5) & 31, oxx = o & 31;
  float s = ob[0];
#pragma unroll
  for (int c = 0; c < 32; ++c)
    s += ow[c] * (float)hp[((size_t)(b * 32 + c) * 32 + oy) * 96 + oxx + 31];
  out[o] = s;
}

extern "C" void kernel_launch(void* const* d_in, const int* in_sizes, int n_in,
                              void* d_out, int out_size, void* d_ws,
                              size_t ws_size, hipStream_t stream) {
  const float* x = (const float*)d_in[0];
  const float* in_w = (const float*)d_in[1];
  const float* in_b = (const float*)d_in[2];
  const float* convs_w = (const float*)d_in[3];
  const float* convs_b = (const float*)d_in[4];
  const float* out_w = (const float*)d_in[5];
  const float* out_b = (const float*)d_in[6];
  float* out = (float*)d_out;

  char* ws = (char*)d_ws;
  f16* xpad = (f16*)ws;                               //    98,304 B
  f16* hpA = (f16*)(ws + 98304);                      // 3,145,728 B
  f16* hpB = (f16*)(ws + 98304 + 3145728);            // 3,145,728 B
  f16* WfIn = (f16*)(ws + 6389760);                   //    65,536 B
  f16* WfH = (f16*)(ws + 6455296);                    // 41,943,040 B
  const bool pre = (ws_size >= 48398336ull);

  pad_x_kernel<<<188, 256, 0, stream>>>(x, xpad);
  if (pre) convert_w3<<<2048, 256, 0, stream>>>(in_w, convs_w, WfIn, WfH);

  if (pre)
    gemm3<1, false, true><<<256, 512, 0, stream>>>(WfIn, xpad, in_b, hpA);
  else
    gemm3<1, false, false><<<256, 512, 0, stream>>>(in_w, xpad, in_b, hpA);

  for (int l = 0; l < 20; ++l) {
    const f16* cur = (l % 2 == 0) ? hpA : hpB;
    f16* nxt = (l % 2 == 0) ? hpB : hpA;
    if (pre)
      gemm3<32, true, true><<<256, 512, 0, stream>>>(
          WfH + (size_t)l * 1048576, cur, convs_b + 32 * l, nxt);
    else
      gemm3<32, true, false><<<256, 512, 0, stream>>>(
          convs_w + (size_t)l * 1048576, cur, convs_b + 32 * l, nxt);
  }

  // after l=19 (odd): output in hpA
  out_conv3<<<64, 256, 0, stream>>>(hpA, out_w, out_b, out);
}